// Round 1
// baseline (985.072 us; speedup 1.0000x reference)
//
#include <hip/hip_runtime.h>
#include <math.h>

// ---------------------------------------------------------------------------
// GIN, 3 layers. Per layer:
//   agg[n] = x[n] + sum_{e: dst[e]==n} ew[e] * x[src[e]]
//   h = relu(agg @ W1 + b1) @ W2 + b2        (relu on h after layers 1,2)
// N=100000, E=1000000, D=64. H = 64 / 128 / 64.
// ---------------------------------------------------------------------------

#define FEAT 64

// ---- float4 copy: init agg = x (fuses the "+x" of the GIN update) ----------
__global__ void copy_f4(const float4* __restrict__ src, float4* __restrict__ dst,
                        int n4) {
    int i = blockIdx.x * blockDim.x + threadIdx.x;
    if (i < n4) dst[i] = src[i];
}

// ---- scatter: one wave per edge, lane = feature ----------------------------
__global__ void scatter_edges(const float* __restrict__ x,
                              const int* __restrict__ srci,
                              const int* __restrict__ dsti,
                              const float* __restrict__ ew,
                              float* agg, int E) {
    int gid  = blockIdx.x * blockDim.x + threadIdx.x;
    int lane = threadIdx.x & 63;
    // e is identical across the 64 lanes of a wave -> force into SGPR so the
    // edge metadata loads go through the scalar pipe.
    int e = __builtin_amdgcn_readfirstlane(gid >> 6);
    if (e >= E) return;
    int   s = srci[e];
    int   d = dsti[e];
    float w = ew[e];
    float v = x[(size_t)s * FEAT + lane] * w;
    unsafeAtomicAdd(&agg[(size_t)d * FEAT + lane], v);  // native global_atomic_add_f32
}

// ---- W1 transpose so MLP k-loop reads contiguous scalar weights ------------
// w1t[j*64+k] = w1[k*H+j]
template<int H>
__global__ void transpose_w1(const float* __restrict__ w1, float* __restrict__ w1t) {
    int i = blockIdx.x * blockDim.x + threadIdx.x;
    if (i < FEAT * H) {
        int j = i >> 6;        // output row    (0..H-1)
        int k = i & 63;        // output column (0..63)
        w1t[i] = w1[k * H + j];
    }
}

// ---- per-node MLP: out = relu(in @ W1 + b1) @ W2 + b2 ----------------------
// One thread per node. All weight indices are wave-uniform -> scalar loads,
// VALU does pure v_fmac v,s,v. x-row and accumulators live in VGPRs.
template<int H, bool RELU_OUT>
__global__ __launch_bounds__(256)
void mlp_node(const float* __restrict__ in, float* __restrict__ out,
              const float* __restrict__ w1t,  // [H][64] (transposed)
              const float* __restrict__ b1,   // [H]
              const float* __restrict__ w2,   // [H][64] (original row-major)
              const float* __restrict__ b2,   // [64]
              int N) {
    int node = blockIdx.x * blockDim.x + threadIdx.x;
    if (node >= N) return;

    float xr[FEAT];
    const float4* xin = reinterpret_cast<const float4*>(in + (size_t)node * FEAT);
#pragma unroll
    for (int i = 0; i < FEAT / 4; ++i) {
        float4 v = xin[i];
        xr[4 * i + 0] = v.x; xr[4 * i + 1] = v.y;
        xr[4 * i + 2] = v.z; xr[4 * i + 3] = v.w;
    }

    float acc[FEAT];
#pragma unroll
    for (int o = 0; o < FEAT; ++o) acc[o] = b2[o];

    for (int j = 0; j < H; ++j) {
        float h = b1[j];
#pragma unroll
        for (int k = 0; k < FEAT; ++k) h += xr[k] * w1t[j * FEAT + k];
        h = fmaxf(h, 0.0f);
#pragma unroll
        for (int o = 0; o < FEAT; ++o) acc[o] += h * w2[j * FEAT + o];
    }

    float4* po = reinterpret_cast<float4*>(out + (size_t)node * FEAT);
#pragma unroll
    for (int i = 0; i < FEAT / 4; ++i) {
        float4 v;
        v.x = acc[4 * i + 0]; v.y = acc[4 * i + 1];
        v.z = acc[4 * i + 2]; v.w = acc[4 * i + 3];
        if (RELU_OUT) {
            v.x = fmaxf(v.x, 0.0f); v.y = fmaxf(v.y, 0.0f);
            v.z = fmaxf(v.z, 0.0f); v.w = fmaxf(v.w, 0.0f);
        }
        po[i] = v;
    }
}

// ---------------------------------------------------------------------------
extern "C" void kernel_launch(void* const* d_in, const int* in_sizes, int n_in,
                              void* d_out, int out_size, void* d_ws, size_t ws_size,
                              hipStream_t stream) {
    const float* x   = (const float*)d_in[0];
    const int*   ei  = (const int*)  d_in[1];
    const float* ew  = (const float*)d_in[2];
    const float* w11 = (const float*)d_in[3];
    const float* b11 = (const float*)d_in[4];
    const float* w12 = (const float*)d_in[5];
    const float* b12 = (const float*)d_in[6];
    const float* w21 = (const float*)d_in[7];
    const float* b21 = (const float*)d_in[8];
    const float* w22 = (const float*)d_in[9];
    const float* b22 = (const float*)d_in[10];
    const float* w31 = (const float*)d_in[11];
    const float* b31 = (const float*)d_in[12];
    const float* w32 = (const float*)d_in[13];
    const float* b32 = (const float*)d_in[14];

    const int N = in_sizes[0] / FEAT;   // 100000
    const int E = in_sizes[2];          // 1000000
    const int* srci = ei;
    const int* dsti = ei + E;

    float* bufA  = (float*)d_ws;                 // [N*64] aggregate scratch
    float* w1t1  = bufA + (size_t)N * FEAT;      // [64*64]
    float* w1t2  = w1t1 + FEAT * 64;             // [128*64]
    float* w1t3  = w1t2 + FEAT * 128;            // [64*64]
    float* bufB  = (float*)d_out;                // [N*64] layer outputs

    const int n4      = N * (FEAT / 4);
    const int cpGrid  = (n4 + 255) / 256;
    const int scGrid  = (E + 3) / 4;             // 4 edges (waves) per 256-block
    const int mlpGrid = (N + 255) / 256;

    // Pre-transpose W1s (once per launch, reused by MLP kernels).
    transpose_w1<64> <<<(FEAT * 64  + 255) / 256, 256, 0, stream>>>(w11, w1t1);
    transpose_w1<128><<<(FEAT * 128 + 255) / 256, 256, 0, stream>>>(w21, w1t2);
    transpose_w1<64> <<<(FEAT * 64  + 255) / 256, 256, 0, stream>>>(w31, w1t3);

    // ---- layer 1 ----
    copy_f4<<<cpGrid, 256, 0, stream>>>((const float4*)x, (float4*)bufA, n4);
    scatter_edges<<<scGrid, 256, 0, stream>>>(x, srci, dsti, ew, bufA, E);
    mlp_node<64, true><<<mlpGrid, 256, 0, stream>>>(bufA, bufB, w1t1, b11, w12, b12, N);

    // ---- layer 2 ----
    copy_f4<<<cpGrid, 256, 0, stream>>>((const float4*)bufB, (float4*)bufA, n4);
    scatter_edges<<<scGrid, 256, 0, stream>>>(bufB, srci, dsti, ew, bufA, E);
    mlp_node<128, true><<<mlpGrid, 256, 0, stream>>>(bufA, bufB, w1t2, b21, w22, b22, N);

    // ---- layer 3 ----
    copy_f4<<<cpGrid, 256, 0, stream>>>((const float4*)bufB, (float4*)bufA, n4);
    scatter_edges<<<scGrid, 256, 0, stream>>>(bufB, srci, dsti, ew, bufA, E);
    mlp_node<64, false><<<mlpGrid, 256, 0, stream>>>(bufA, bufB, w1t3, b31, b32 ? w32 : w32, b32, N);
}

// Round 2
// 913.987 us; speedup vs baseline: 1.0778x; 1.0778x over previous
//
#include <hip/hip_runtime.h>
#include <math.h>

// ---------------------------------------------------------------------------
// GIN, 3 layers, N=100000 nodes, E=1000000 edges, D=64, fp32.
// Round 2: CSR-gather aggregation (no atomics on features) + fused
// block-parallel MLP (LDS-staged hidden layer, no h round-trip to HBM).
// ---------------------------------------------------------------------------

#define FEAT 64

// ---------------- CSR build ------------------------------------------------
__global__ void k_zero(int* p, int n) {
    int i = blockIdx.x * 256 + threadIdx.x;
    if (i < n) p[i] = 0;
}

__global__ void k_hist(const int* __restrict__ dst, int* __restrict__ deg, int E) {
    int e = blockIdx.x * 256 + threadIdx.x;
    if (e < E) atomicAdd(&deg[dst[e]], 1);
}

// block-level exclusive scan (256 elems/block) + block sums
__global__ void k_scan1(const int* __restrict__ deg, int* __restrict__ part,
                        int* __restrict__ bsums, int n) {
    __shared__ int tmp[256];
    int tid = threadIdx.x;
    int i = blockIdx.x * 256 + tid;
    int v = (i < n) ? deg[i] : 0;
    tmp[tid] = v;
    __syncthreads();
    for (int off = 1; off < 256; off <<= 1) {
        int t = (tid >= off) ? tmp[tid - off] : 0;
        __syncthreads();
        tmp[tid] += t;
        __syncthreads();
    }
    if (i < n) part[i] = tmp[tid] - v;           // exclusive
    if (tid == 255) bsums[blockIdx.x] = tmp[255]; // inclusive block total
}

// single-block exclusive scan of block sums (nb <= 512)
__global__ void k_scan2(int* bsums, int nb) {
    __shared__ int tmp[512];
    int tid = threadIdx.x;
    int v = (tid < nb) ? bsums[tid] : 0;
    tmp[tid] = v;
    __syncthreads();
    for (int off = 1; off < 512; off <<= 1) {
        int t = (tid >= off) ? tmp[tid - off] : 0;
        __syncthreads();
        tmp[tid] += t;
        __syncthreads();
    }
    if (tid < nb) bsums[tid] = tmp[tid] - v;
}

__global__ void k_add(int* __restrict__ rowptr, int* __restrict__ pos,
                      const int* __restrict__ bsums, int n, int E) {
    int i = blockIdx.x * 256 + threadIdx.x;
    if (i < n) {
        int v = rowptr[i] + bsums[i >> 8];
        rowptr[i] = v;
        pos[i] = v;
    } else if (i == n) {
        rowptr[n] = E;
    }
}

__global__ void k_fill(const int* __restrict__ src, const int* __restrict__ dst,
                       const float* __restrict__ ew, int* __restrict__ pos,
                       int* __restrict__ csr_s, float* __restrict__ csr_w, int E) {
    int e = blockIdx.x * 256 + threadIdx.x;
    if (e < E) {
        int d = dst[e];
        int slot = atomicAdd(&pos[d], 1);
        csr_s[slot] = src[e];
        csr_w[slot] = ew[e];
    }
}

// ---------------- aggregation: one wave per node, lane = feature -----------
// agg[n] = in[n] + sum_{e in CSR row n} w_e * in[src_e]
__global__ __launch_bounds__(256)
void k_gather(const float* __restrict__ in, float* __restrict__ agg,
              const int* __restrict__ rowptr, const int* __restrict__ csr_s,
              const float* __restrict__ csr_w, int N) {
    int wid = (blockIdx.x * 256 + threadIdx.x) >> 6;
    int lane = threadIdx.x & 63;
    wid = __builtin_amdgcn_readfirstlane(wid);   // wave-uniform -> scalar pipe
    if (wid >= N) return;
    int beg = rowptr[wid];
    int end = rowptr[wid + 1];
    float acc = in[(size_t)wid * FEAT + lane];   // fuses the "+x"
    for (int p = beg; p < end; ++p) {
        int s = csr_s[p];                        // uniform -> s_load
        float w = csr_w[p];
        acc += w * in[(size_t)s * FEAT + lane];  // 256B coalesced row read
    }
    agg[(size_t)wid * FEAT + lane] = acc;
}

// ---------------- fused 2-layer MLP, LDS-staged hidden ---------------------
// phase1: thread (node, j-quad) computes 4 hidden units -> LDS (with relu)
// phase2: thread (node, o-group) computes outputs from LDS hidden row
template<int H, bool RELU_OUT>
__global__ __launch_bounds__(256)
void k_mlp(const float* __restrict__ in, float* __restrict__ out,
           const float* __restrict__ w1, const float* __restrict__ b1,
           const float* __restrict__ w2, const float* __restrict__ b2, int N) {
    constexpr int JQ  = H / 4;        // j-quads per node: 16 (H=64), 32 (H=128)
    constexpr int NB  = 256 / JQ;     // nodes per block: 16 or 8
    constexpr int STR = H + 4;        // LDS row stride (bank-conflict pad, /4 aligned)
    __shared__ float hs[NB * STR];

    int tid = threadIdx.x;
    int nl  = tid / JQ;
    int j4  = tid % JQ;
    int node = blockIdx.x * NB + nl;

    if (node < N) {
        // load agg row into registers (lanes of same node broadcast via L1)
        float xr[FEAT];
        const float4* xin = reinterpret_cast<const float4*>(in + (size_t)node * FEAT);
#pragma unroll
        for (int i = 0; i < FEAT / 4; ++i) {
            float4 v = xin[i];
            xr[4*i] = v.x; xr[4*i+1] = v.y; xr[4*i+2] = v.z; xr[4*i+3] = v.w;
        }
        // 4 hidden units: w1 is [64][H] row-major -> float4 per k, coalesced
        const float4* wq = reinterpret_cast<const float4*>(w1);
        float4 bv = reinterpret_cast<const float4*>(b1)[j4];
        float a0 = bv.x, a1 = bv.y, a2 = bv.z, a3 = bv.w;
#pragma unroll
        for (int k = 0; k < FEAT; ++k) {
            float4 w = wq[k * JQ + j4];
            float xv = xr[k];
            a0 = fmaf(xv, w.x, a0); a1 = fmaf(xv, w.y, a1);
            a2 = fmaf(xv, w.z, a2); a3 = fmaf(xv, w.w, a3);
        }
        float4 h4;
        h4.x = fmaxf(a0, 0.f); h4.y = fmaxf(a1, 0.f);
        h4.z = fmaxf(a2, 0.f); h4.w = fmaxf(a3, 0.f);
        *reinterpret_cast<float4*>(&hs[nl * STR + 4 * j4]) = h4;
    }
    __syncthreads();

    if constexpr (H == 64) {
        int nl2 = tid >> 4, o4 = tid & 15;       // 16 nodes x 16 out-quads
        int node2 = blockIdx.x * NB + nl2;
        if (node2 < N) {
            const float4* wq2 = reinterpret_cast<const float4*>(w2); // [H][64]
            float4 bv = reinterpret_cast<const float4*>(b2)[o4];
            float a0 = bv.x, a1 = bv.y, a2 = bv.z, a3 = bv.w;
            const float* hrow = &hs[nl2 * STR];
#pragma unroll
            for (int j = 0; j < H; ++j) {
                float hv = hrow[j];              // LDS broadcast
                float4 w = wq2[j * 16 + o4];     // coalesced row read
                a0 = fmaf(hv, w.x, a0); a1 = fmaf(hv, w.y, a1);
                a2 = fmaf(hv, w.z, a2); a3 = fmaf(hv, w.w, a3);
            }
            if (RELU_OUT) {
                a0 = fmaxf(a0, 0.f); a1 = fmaxf(a1, 0.f);
                a2 = fmaxf(a2, 0.f); a3 = fmaxf(a3, 0.f);
            }
            float4 ov; ov.x = a0; ov.y = a1; ov.z = a2; ov.w = a3;
            reinterpret_cast<float4*>(out + (size_t)node2 * FEAT)[o4] = ov;
        }
    } else {
        int nl2 = tid >> 5, o2 = tid & 31;       // 8 nodes x 32 out-pairs
        int node2 = blockIdx.x * NB + nl2;
        if (node2 < N) {
            const float2* wq2 = reinterpret_cast<const float2*>(w2); // [H][64]
            float2 bv = reinterpret_cast<const float2*>(b2)[o2];
            float a0 = bv.x, a1 = bv.y;
            const float* hrow = &hs[nl2 * STR];
#pragma unroll
            for (int j = 0; j < H; ++j) {
                float hv = hrow[j];
                float2 w = wq2[j * 32 + o2];
                a0 = fmaf(hv, w.x, a0); a1 = fmaf(hv, w.y, a1);
            }
            if (RELU_OUT) { a0 = fmaxf(a0, 0.f); a1 = fmaxf(a1, 0.f); }
            float2 ov; ov.x = a0; ov.y = a1;
            reinterpret_cast<float2*>(out + (size_t)node2 * FEAT)[o2] = ov;
        }
    }
}

// ---------------------------------------------------------------------------
extern "C" void kernel_launch(void* const* d_in, const int* in_sizes, int n_in,
                              void* d_out, int out_size, void* d_ws, size_t ws_size,
                              hipStream_t stream) {
    const float* x   = (const float*)d_in[0];
    const int*   ei  = (const int*)  d_in[1];
    const float* ew  = (const float*)d_in[2];
    const float* w11 = (const float*)d_in[3];
    const float* b11 = (const float*)d_in[4];
    const float* w12 = (const float*)d_in[5];
    const float* b12 = (const float*)d_in[6];
    const float* w21 = (const float*)d_in[7];
    const float* b21 = (const float*)d_in[8];
    const float* w22 = (const float*)d_in[9];
    const float* b22 = (const float*)d_in[10];
    const float* w31 = (const float*)d_in[11];
    const float* b31 = (const float*)d_in[12];
    const float* w32 = (const float*)d_in[13];
    const float* b32 = (const float*)d_in[14];

    const int N = in_sizes[0] / FEAT;   // 100000
    const int E = in_sizes[2];          // 1000000
    const int* srci = ei;
    const int* dsti = ei + E;

    // workspace layout (~35 MB)
    float* agg    = (float*)d_ws;                       // [N*64]
    int*   rowptr = (int*)(agg + (size_t)N * FEAT);     // [N+1]
    int*   pos    = rowptr + (N + 1);                   // [N]
    int*   deg    = pos + N;                            // [N]
    int*   bsums  = deg + N;                            // [512]
    int*   csr_s  = bsums + 512;                        // [E]
    float* csr_w  = (float*)(csr_s + E);                // [E]
    float* outF   = (float*)d_out;                      // [N*64]

    const int gE   = (E + 255) / 256;
    const int gN   = (N + 255) / 256;
    const int nb1  = (N + 255) / 256;                   // scan blocks (391)
    const int gN1  = (N + 1 + 255) / 256;
    const int gGat = (N * 64 + 255) / 256;              // one wave per node
    const int gM64 = (N + 15) / 16;
    const int gM128= (N + 7) / 8;

    // ---- CSR build (once, reused by all 3 layers) ----
    k_zero <<<gN,  256, 0, stream>>>(deg, N);
    k_hist <<<gE,  256, 0, stream>>>(dsti, deg, E);
    k_scan1<<<nb1, 256, 0, stream>>>(deg, rowptr, bsums, N);
    k_scan2<<<1,   512, 0, stream>>>(bsums, nb1);
    k_add  <<<gN1, 256, 0, stream>>>(rowptr, pos, bsums, N, E);
    k_fill <<<gE,  256, 0, stream>>>(srci, dsti, ew, pos, csr_s, csr_w, E);

    // ---- layer 1 ----
    k_gather<<<gGat, 256, 0, stream>>>(x, agg, rowptr, csr_s, csr_w, N);
    k_mlp<64,  true ><<<gM64,  256, 0, stream>>>(agg, outF, w11, b11, w12, b12, N);
    // ---- layer 2 ----
    k_gather<<<gGat, 256, 0, stream>>>(outF, agg, rowptr, csr_s, csr_w, N);
    k_mlp<128, true ><<<gM128, 256, 0, stream>>>(agg, outF, w21, b21, w22, b22, N);
    // ---- layer 3 ----
    k_gather<<<gGat, 256, 0, stream>>>(outF, agg, rowptr, csr_s, csr_w, N);
    k_mlp<64,  false><<<gM64,  256, 0, stream>>>(agg, outF, w31, b31, w32, b32, N);
}

// Round 3
// 567.970 us; speedup vs baseline: 1.7344x; 1.6092x over previous
//
#include <hip/hip_runtime.h>
#include <math.h>

// ---------------------------------------------------------------------------
// GIN, 3 layers, N=100000 nodes, E=1000000 edges, D=64, fp32.
// Round 3: register-tiled block-GEMM MLP (64 nodes/block, 4x4 outer product
// per thread, LDS A/h tiles with free <=2-way bank aliasing, weights streamed
// from L1). CSR build + wave-per-node gather unchanged from round 2.
// ---------------------------------------------------------------------------

#define FEAT 64

// ---------------- CSR build ------------------------------------------------
__global__ void k_zero(int* p, int n) {
    int i = blockIdx.x * 256 + threadIdx.x;
    if (i < n) p[i] = 0;
}

__global__ void k_hist(const int* __restrict__ dst, int* __restrict__ deg, int E) {
    int e = blockIdx.x * 256 + threadIdx.x;
    if (e < E) atomicAdd(&deg[dst[e]], 1);
}

__global__ void k_scan1(const int* __restrict__ deg, int* __restrict__ part,
                        int* __restrict__ bsums, int n) {
    __shared__ int tmp[256];
    int tid = threadIdx.x;
    int i = blockIdx.x * 256 + tid;
    int v = (i < n) ? deg[i] : 0;
    tmp[tid] = v;
    __syncthreads();
    for (int off = 1; off < 256; off <<= 1) {
        int t = (tid >= off) ? tmp[tid - off] : 0;
        __syncthreads();
        tmp[tid] += t;
        __syncthreads();
    }
    if (i < n) part[i] = tmp[tid] - v;            // exclusive
    if (tid == 255) bsums[blockIdx.x] = tmp[255]; // block total
}

__global__ void k_scan2(int* bsums, int nb) {
    __shared__ int tmp[512];
    int tid = threadIdx.x;
    int v = (tid < nb) ? bsums[tid] : 0;
    tmp[tid] = v;
    __syncthreads();
    for (int off = 1; off < 512; off <<= 1) {
        int t = (tid >= off) ? tmp[tid - off] : 0;
        __syncthreads();
        tmp[tid] += t;
        __syncthreads();
    }
    if (tid < nb) bsums[tid] = tmp[tid] - v;
}

__global__ void k_add(int* __restrict__ rowptr, int* __restrict__ pos,
                      const int* __restrict__ bsums, int n, int E) {
    int i = blockIdx.x * 256 + threadIdx.x;
    if (i < n) {
        int v = rowptr[i] + bsums[i >> 8];
        rowptr[i] = v;
        pos[i] = v;
    } else if (i == n) {
        rowptr[n] = E;
    }
}

__global__ void k_fill(const int* __restrict__ src, const int* __restrict__ dst,
                       const float* __restrict__ ew, int* __restrict__ pos,
                       int* __restrict__ csr_s, float* __restrict__ csr_w, int E) {
    int e = blockIdx.x * 256 + threadIdx.x;
    if (e < E) {
        int d = dst[e];
        int slot = atomicAdd(&pos[d], 1);
        csr_s[slot] = src[e];
        csr_w[slot] = ew[e];
    }
}

// ---------------- aggregation: one wave per node, lane = feature -----------
__global__ __launch_bounds__(256)
void k_gather(const float* __restrict__ in, float* __restrict__ agg,
              const int* __restrict__ rowptr, const int* __restrict__ csr_s,
              const float* __restrict__ csr_w, int N) {
    int wid = (blockIdx.x * 256 + threadIdx.x) >> 6;
    int lane = threadIdx.x & 63;
    wid = __builtin_amdgcn_readfirstlane(wid);
    if (wid >= N) return;
    int beg = rowptr[wid];
    int end = rowptr[wid + 1];
    float acc = in[(size_t)wid * FEAT + lane];   // fuses the "+x"
    for (int p = beg; p < end; ++p) {
        int s = csr_s[p];
        float w = csr_w[p];
        acc += w * in[(size_t)s * FEAT + lane];
    }
    agg[(size_t)wid * FEAT + lane] = acc;
}

// ---------------- fused 2-layer MLP, register-tiled ------------------------
// Block = 256 threads = 64 nodes. Thread (tn = t>>4, th = t&15) computes a
// 4-node x 4-col (x2 for H=128) outer-product tile. A staged in LDS stride 68
// (<=2-way bank aliasing = free); h overlays A after a sync. Weights streamed
// from global: one 256B contiguous row-chunk per wave per k -> L1-resident.
template<int H, bool RELU_OUT>
__global__ __launch_bounds__(256)
void k_mlp2(const float* __restrict__ in, float* __restrict__ out,
            const float* __restrict__ w1, const float* __restrict__ b1,
            const float* __restrict__ w2, const float* __restrict__ b2, int N) {
    constexpr int SA  = 68;                 // A-tile stride (floats)
    constexpr int SH  = H + 4;              // h-tile stride
    constexpr int BUF = 64 * (SH > SA ? SH : SA);
    constexpr int HQ  = H / 64;             // col-quads per thread (1 or 2)
    __shared__ float S[BUF];

    const int t = threadIdx.x;
    const int node0 = blockIdx.x * 64;
    const int tn = t >> 4;                  // node-quad 0..15
    const int th = t & 15;                  // col-quad  0..15

    // ---- stage A tile: 64 nodes x 16 float4, coalesced ----
#pragma unroll
    for (int it = 0; it < 4; ++it) {
        int idx = it * 256 + t;             // float4 index in tile
        int n = idx >> 4, q = idx & 15;
        float4 v = make_float4(0.f, 0.f, 0.f, 0.f);
        if (node0 + n < N)
            v = reinterpret_cast<const float4*>(in)[(size_t)(node0 + n) * 16 + q];
        *reinterpret_cast<float4*>(&S[n * SA + 4 * q]) = v;
    }
    __syncthreads();

    // ---- phase 1: h = relu(A @ W1 + b1) ----
    float4 bv[HQ];
#pragma unroll
    for (int u = 0; u < HQ; ++u)
        bv[u] = reinterpret_cast<const float4*>(b1)[th + 16 * u];

    float c[4][4 * HQ];
#pragma unroll
    for (int i = 0; i < 4; ++i)
#pragma unroll
        for (int u = 0; u < 4 * HQ; ++u) c[i][u] = 0.f;

#pragma unroll 8
    for (int k = 0; k < FEAT; ++k) {
        float a0 = S[(4 * tn + 0) * SA + k];
        float a1 = S[(4 * tn + 1) * SA + k];
        float a2 = S[(4 * tn + 2) * SA + k];
        float a3 = S[(4 * tn + 3) * SA + k];
#pragma unroll
        for (int u = 0; u < HQ; ++u) {
            float4 w = reinterpret_cast<const float4*>(w1 + (size_t)k * H)[th + 16 * u];
            c[0][4*u+0] = fmaf(a0, w.x, c[0][4*u+0]);
            c[0][4*u+1] = fmaf(a0, w.y, c[0][4*u+1]);
            c[0][4*u+2] = fmaf(a0, w.z, c[0][4*u+2]);
            c[0][4*u+3] = fmaf(a0, w.w, c[0][4*u+3]);
            c[1][4*u+0] = fmaf(a1, w.x, c[1][4*u+0]);
            c[1][4*u+1] = fmaf(a1, w.y, c[1][4*u+1]);
            c[1][4*u+2] = fmaf(a1, w.z, c[1][4*u+2]);
            c[1][4*u+3] = fmaf(a1, w.w, c[1][4*u+3]);
            c[2][4*u+0] = fmaf(a2, w.x, c[2][4*u+0]);
            c[2][4*u+1] = fmaf(a2, w.y, c[2][4*u+1]);
            c[2][4*u+2] = fmaf(a2, w.z, c[2][4*u+2]);
            c[2][4*u+3] = fmaf(a2, w.w, c[2][4*u+3]);
            c[3][4*u+0] = fmaf(a3, w.x, c[3][4*u+0]);
            c[3][4*u+1] = fmaf(a3, w.y, c[3][4*u+1]);
            c[3][4*u+2] = fmaf(a3, w.z, c[3][4*u+2]);
            c[3][4*u+3] = fmaf(a3, w.w, c[3][4*u+3]);
        }
    }
    __syncthreads();   // all A reads done -> safe to overlay h on S

    // write h (relu + bias) into S with stride SH
#pragma unroll
    for (int i = 0; i < 4; ++i) {
#pragma unroll
        for (int u = 0; u < HQ; ++u) {
            float4 h4;
            h4.x = fmaxf(c[i][4*u+0] + bv[u].x, 0.f);
            h4.y = fmaxf(c[i][4*u+1] + bv[u].y, 0.f);
            h4.z = fmaxf(c[i][4*u+2] + bv[u].z, 0.f);
            h4.w = fmaxf(c[i][4*u+3] + bv[u].w, 0.f);
            *reinterpret_cast<float4*>(&S[(4 * tn + i) * SH + 4 * (th + 16 * u)]) = h4;
        }
    }
    __syncthreads();

    // ---- phase 2: out = h @ W2 + b2 ----
    float4 b2v = reinterpret_cast<const float4*>(b2)[th];
    float o[4][4];
#pragma unroll
    for (int i = 0; i < 4; ++i)
#pragma unroll
        for (int u = 0; u < 4; ++u) o[i][u] = 0.f;

#pragma unroll 8
    for (int j = 0; j < H; ++j) {
        float a0 = S[(4 * tn + 0) * SH + j];
        float a1 = S[(4 * tn + 1) * SH + j];
        float a2 = S[(4 * tn + 2) * SH + j];
        float a3 = S[(4 * tn + 3) * SH + j];
        float4 w = reinterpret_cast<const float4*>(w2 + (size_t)j * FEAT)[th];
        o[0][0] = fmaf(a0, w.x, o[0][0]);
        o[0][1] = fmaf(a0, w.y, o[0][1]);
        o[0][2] = fmaf(a0, w.z, o[0][2]);
        o[0][3] = fmaf(a0, w.w, o[0][3]);
        o[1][0] = fmaf(a1, w.x, o[1][0]);
        o[1][1] = fmaf(a1, w.y, o[1][1]);
        o[1][2] = fmaf(a1, w.z, o[1][2]);
        o[1][3] = fmaf(a1, w.w, o[1][3]);
        o[2][0] = fmaf(a2, w.x, o[2][0]);
        o[2][1] = fmaf(a2, w.y, o[2][1]);
        o[2][2] = fmaf(a2, w.z, o[2][2]);
        o[2][3] = fmaf(a2, w.w, o[2][3]);
        o[3][0] = fmaf(a3, w.x, o[3][0]);
        o[3][1] = fmaf(a3, w.y, o[3][1]);
        o[3][2] = fmaf(a3, w.z, o[3][2]);
        o[3][3] = fmaf(a3, w.w, o[3][3]);
    }

#pragma unroll
    for (int i = 0; i < 4; ++i) {
        int n = node0 + 4 * tn + i;
        if (n < N) {
            float4 v;
            v.x = o[i][0] + b2v.x;
            v.y = o[i][1] + b2v.y;
            v.z = o[i][2] + b2v.z;
            v.w = o[i][3] + b2v.w;
            if (RELU_OUT) {
                v.x = fmaxf(v.x, 0.f); v.y = fmaxf(v.y, 0.f);
                v.z = fmaxf(v.z, 0.f); v.w = fmaxf(v.w, 0.f);
            }
            reinterpret_cast<float4*>(out)[(size_t)n * 16 + th] = v;
        }
    }
}

// ---------------------------------------------------------------------------
extern "C" void kernel_launch(void* const* d_in, const int* in_sizes, int n_in,
                              void* d_out, int out_size, void* d_ws, size_t ws_size,
                              hipStream_t stream) {
    const float* x   = (const float*)d_in[0];
    const int*   ei  = (const int*)  d_in[1];
    const float* ew  = (const float*)d_in[2];
    const float* w11 = (const float*)d_in[3];
    const float* b11 = (const float*)d_in[4];
    const float* w12 = (const float*)d_in[5];
    const float* b12 = (const float*)d_in[6];
    const float* w21 = (const float*)d_in[7];
    const float* b21 = (const float*)d_in[8];
    const float* w22 = (const float*)d_in[9];
    const float* b22 = (const float*)d_in[10];
    const float* w31 = (const float*)d_in[11];
    const float* b31 = (const float*)d_in[12];
    const float* w32 = (const float*)d_in[13];
    const float* b32 = (const float*)d_in[14];

    const int N = in_sizes[0] / FEAT;   // 100000
    const int E = in_sizes[2];          // 1000000
    const int* srci = ei;
    const int* dsti = ei + E;

    // workspace layout (~35 MB)
    float* agg    = (float*)d_ws;                       // [N*64]
    int*   rowptr = (int*)(agg + (size_t)N * FEAT);     // [N+1]
    int*   pos    = rowptr + (N + 1);                   // [N]
    int*   deg    = pos + N;                            // [N]
    int*   bsums  = deg + N;                            // [512]
    int*   csr_s  = bsums + 512;                        // [E]
    float* csr_w  = (float*)(csr_s + E);                // [E]
    float* outF   = (float*)d_out;                      // [N*64]

    const int gE   = (E + 255) / 256;
    const int gN   = (N + 255) / 256;
    const int nb1  = (N + 255) / 256;
    const int gN1  = (N + 1 + 255) / 256;
    const int gGat = (N * 64 + 255) / 256;
    const int gMlp = (N + 63) / 64;

    // ---- CSR build (once, reused by all 3 layers) ----
    k_zero <<<gN,  256, 0, stream>>>(deg, N);
    k_hist <<<gE,  256, 0, stream>>>(dsti, deg, E);
    k_scan1<<<nb1, 256, 0, stream>>>(deg, rowptr, bsums, N);
    k_scan2<<<1,   512, 0, stream>>>(bsums, nb1);
    k_add  <<<gN1, 256, 0, stream>>>(rowptr, pos, bsums, N, E);
    k_fill <<<gE,  256, 0, stream>>>(srci, dsti, ew, pos, csr_s, csr_w, E);

    // ---- layer 1 ----
    k_gather<<<gGat, 256, 0, stream>>>(x, agg, rowptr, csr_s, csr_w, N);
    k_mlp2<64,  true ><<<gMlp, 256, 0, stream>>>(agg, outF, w11, b11, w12, b12, N);
    // ---- layer 2 ----
    k_gather<<<gGat, 256, 0, stream>>>(outF, agg, rowptr, csr_s, csr_w, N);
    k_mlp2<128, true ><<<gMlp, 256, 0, stream>>>(agg, outF, w21, b21, w22, b22, N);
    // ---- layer 3 ----
    k_gather<<<gGat, 256, 0, stream>>>(outF, agg, rowptr, csr_s, csr_w, N);
    k_mlp2<64,  false><<<gMlp, 256, 0, stream>>>(agg, outF, w31, b31, w32, b32, N);
}

// Round 4
// 432.401 us; speedup vs baseline: 2.2781x; 1.3135x over previous
//
#include <hip/hip_runtime.h>
#include <math.h>

// ---------------------------------------------------------------------------
// GIN, 3 layers, N=100000, E=1000000, D=64, fp32 in/out.
// Round 4:
//  - MLP via bf16x3 split-precision MFMA (16x16x32), weights pre-packed into
//    B-fragment order (hi/lo), h staged in wave-private LDS tile.
//  - Gather: 4 edge-slots/wave x float4 feature lanes, 8 edges/iter,
//    __shfl_xor butterfly reduce.
//  - CSR build unchanged.
// ---------------------------------------------------------------------------

#define FEAT 64

typedef __attribute__((ext_vector_type(8))) short bfrag;   // 8 bf16 (4 VGPRs)
typedef __attribute__((ext_vector_type(4))) float ffrag;   // 4 fp32 acc

__device__ __forceinline__ unsigned short f2bf_rne(float x) {
    union { float f; unsigned u; } v; v.f = x;
    unsigned r = (v.u + 0x7fffu + ((v.u >> 16) & 1u)) >> 16;
    return (unsigned short)r;
}
__device__ __forceinline__ float bf2f(unsigned short h) {
    union { unsigned u; float f; } v; v.u = ((unsigned)h) << 16;
    return v.f;
}

// ---------------- CSR build ------------------------------------------------
__global__ void k_zero(int* p, int n) {
    int i = blockIdx.x * 256 + threadIdx.x;
    if (i < n) p[i] = 0;
}

__global__ void k_hist(const int* __restrict__ dst, int* __restrict__ deg, int E) {
    int e = blockIdx.x * 256 + threadIdx.x;
    if (e < E) atomicAdd(&deg[dst[e]], 1);
}

__global__ void k_scan1(const int* __restrict__ deg, int* __restrict__ part,
                        int* __restrict__ bsums, int n) {
    __shared__ int tmp[256];
    int tid = threadIdx.x;
    int i = blockIdx.x * 256 + tid;
    int v = (i < n) ? deg[i] : 0;
    tmp[tid] = v;
    __syncthreads();
    for (int off = 1; off < 256; off <<= 1) {
        int t = (tid >= off) ? tmp[tid - off] : 0;
        __syncthreads();
        tmp[tid] += t;
        __syncthreads();
    }
    if (i < n) part[i] = tmp[tid] - v;            // exclusive
    if (tid == 255) bsums[blockIdx.x] = tmp[255]; // block total
}

__global__ void k_scan2(int* bsums, int nb) {
    __shared__ int tmp[512];
    int tid = threadIdx.x;
    int v = (tid < nb) ? bsums[tid] : 0;
    tmp[tid] = v;
    __syncthreads();
    for (int off = 1; off < 512; off <<= 1) {
        int t = (tid >= off) ? tmp[tid - off] : 0;
        __syncthreads();
        tmp[tid] += t;
        __syncthreads();
    }
    if (tid < nb) bsums[tid] = tmp[tid] - v;
}

__global__ void k_add(int* __restrict__ rowptr, int* __restrict__ pos,
                      const int* __restrict__ bsums, int n, int E) {
    int i = blockIdx.x * 256 + threadIdx.x;
    if (i < n) {
        int v = rowptr[i] + bsums[i >> 8];
        rowptr[i] = v;
        pos[i] = v;
    } else if (i == n) {
        rowptr[n] = E;
    }
}

__global__ void k_fill(const int* __restrict__ src, const int* __restrict__ dst,
                       const float* __restrict__ ew, int* __restrict__ pos,
                       int* __restrict__ csr_s, float* __restrict__ csr_w, int E) {
    int e = blockIdx.x * 256 + threadIdx.x;
    if (e < E) {
        int d = dst[e];
        int slot = atomicAdd(&pos[d], 1);
        csr_s[slot] = src[e];
        csr_w[slot] = ew[e];
    }
}

// ---------------- weight pack: [K][Hc] fp32 -> B-frag-ordered bf16 hi/lo ---
// frag element i: j = i&7, lane = (i>>3)&63, fb = i>>9, kf = fb%KF, cg = fb/KF
// source: k = kf*32 + (lane>>4)*8 + j ; col = cg*16 + (lane&15)
__global__ void k_pack(const float* __restrict__ w, unsigned short* __restrict__ hi,
                       unsigned short* __restrict__ lo, int K, int Hc) {
    int i = blockIdx.x * 256 + threadIdx.x;
    if (i >= K * Hc) return;
    int KF = K >> 5;
    int j    = i & 7;
    int lane = (i >> 3) & 63;
    int fb   = i >> 9;
    int kf   = fb % KF;
    int cg   = fb / KF;
    int k    = kf * 32 + ((lane >> 4) << 3) + j;
    int col  = cg * 16 + (lane & 15);
    float x = w[k * Hc + col];
    unsigned short h = f2bf_rne(x);
    hi[i] = h;
    lo[i] = f2bf_rne(x - bf2f(h));
}

// ---------------- gather: wave=node, 4 edge-slots x 16 float4-lanes --------
__global__ __launch_bounds__(256)
void k_gather2(const float* __restrict__ in, float* __restrict__ agg,
               const int* __restrict__ rowptr, const int* __restrict__ csr_s,
               const float* __restrict__ csr_w, int N) {
    int wid = (blockIdx.x * 256 + threadIdx.x) >> 6;
    int lane = threadIdx.x & 63;
    wid = __builtin_amdgcn_readfirstlane(wid);
    if (wid >= N) return;
    const int qw = lane >> 4;   // edge slot 0..3
    const int f  = lane & 15;   // feature quad
    const int beg = rowptr[wid];
    const int end = rowptr[wid + 1];
    const float4* in4 = reinterpret_cast<const float4*>(in);

    float4 acc = make_float4(0.f, 0.f, 0.f, 0.f);
    for (int p = beg; p < end; p += 8) {
        int i0 = p + qw, i1 = p + 4 + qw;
        int s0 = 0, s1 = 0;
        float w0 = 0.f, w1 = 0.f;
        if (i0 < end) { s0 = csr_s[i0]; w0 = csr_w[i0]; }
        if (i1 < end) { s1 = csr_s[i1]; w1 = csr_w[i1]; }
        float4 v0 = in4[(size_t)s0 * 16 + f];
        float4 v1 = in4[(size_t)s1 * 16 + f];
        acc.x = fmaf(w0, v0.x, acc.x); acc.y = fmaf(w0, v0.y, acc.y);
        acc.z = fmaf(w0, v0.z, acc.z); acc.w = fmaf(w0, v0.w, acc.w);
        acc.x = fmaf(w1, v1.x, acc.x); acc.y = fmaf(w1, v1.y, acc.y);
        acc.z = fmaf(w1, v1.z, acc.z); acc.w = fmaf(w1, v1.w, acc.w);
    }
    // butterfly across the 4 edge-slots (lane bits 4,5)
    acc.x += __shfl_xor(acc.x, 16); acc.y += __shfl_xor(acc.y, 16);
    acc.z += __shfl_xor(acc.z, 16); acc.w += __shfl_xor(acc.w, 16);
    acc.x += __shfl_xor(acc.x, 32); acc.y += __shfl_xor(acc.y, 32);
    acc.z += __shfl_xor(acc.z, 32); acc.w += __shfl_xor(acc.w, 32);

    float4 xr = in4[(size_t)wid * 16 + f];   // fuse the "+x"
    acc.x += xr.x; acc.y += xr.y; acc.z += xr.z; acc.w += xr.w;
    if (qw == 0)
        reinterpret_cast<float4*>(agg)[(size_t)wid * 16 + f] = acc;
}

// ---------------- MFMA MLP: out = relu?(relu(A@W1+b1)@W2+b2) ---------------
// Block 256 = 4 waves, 16 nodes/wave. bf16x3 split precision.
template<int H, bool RELU_OUT>
__global__ __launch_bounds__(256)
void k_mlp3(const float* __restrict__ in, float* __restrict__ out,
            const unsigned short* __restrict__ w1h, const unsigned short* __restrict__ w1l,
            const float* __restrict__ b1,
            const unsigned short* __restrict__ w2h, const unsigned short* __restrict__ w2l,
            const float* __restrict__ b2, int N) {
    constexpr int SH  = H + 4;      // LDS h-row stride: 2-way bank alias only
    constexpr int CG1 = H / 16;     // phase-1 col groups
    constexpr int KF2 = H / 32;     // phase-2 k frags
    __shared__ float hs[4 * 16 * SH];

    const int t = threadIdx.x;
    const int wv = t >> 6, lane = t & 63;
    const int m = lane & 15, q = lane >> 4;
    const int node0 = blockIdx.x * 64 + wv * 16;
    float* hw = &hs[wv * 16 * SH];

    const bfrag* w1hp = reinterpret_cast<const bfrag*>(w1h);
    const bfrag* w1lp = reinterpret_cast<const bfrag*>(w1l);
    const bfrag* w2hp = reinterpret_cast<const bfrag*>(w2h);
    const bfrag* w2lp = reinterpret_cast<const bfrag*>(w2l);

    // ---- load A frags (K=64 -> 2 kf), split hi/lo ----
    bfrag ah[2], al[2];
    const int nodeA = node0 + m;
#pragma unroll
    for (int kf = 0; kf < 2; ++kf) {
        float u[8] = {0.f, 0.f, 0.f, 0.f, 0.f, 0.f, 0.f, 0.f};
        if (nodeA < N) {
            const float* base = in + (size_t)nodeA * FEAT + kf * 32 + q * 8;
            float4 u0 = *reinterpret_cast<const float4*>(base);
            float4 u1 = *reinterpret_cast<const float4*>(base + 4);
            u[0] = u0.x; u[1] = u0.y; u[2] = u0.z; u[3] = u0.w;
            u[4] = u1.x; u[5] = u1.y; u[6] = u1.z; u[7] = u1.w;
        }
#pragma unroll
        for (int j = 0; j < 8; ++j) {
            unsigned short hb = f2bf_rne(u[j]);
            ah[kf][j] = (short)hb;
            al[kf][j] = (short)f2bf_rne(u[j] - bf2f(hb));
        }
    }

    // ---- phase 1: h = relu(A@W1 + b1) -> LDS (wave-private tile) ----
#pragma unroll
    for (int cg = 0; cg < CG1; ++cg) {
        ffrag c = {0.f, 0.f, 0.f, 0.f};
#pragma unroll
        for (int kf = 0; kf < 2; ++kf) {
            bfrag bh = w1hp[(cg * 2 + kf) * 64 + lane];
            bfrag bl = w1lp[(cg * 2 + kf) * 64 + lane];
            c = __builtin_amdgcn_mfma_f32_16x16x32_bf16(ah[kf], bh, c, 0, 0, 0);
            c = __builtin_amdgcn_mfma_f32_16x16x32_bf16(al[kf], bh, c, 0, 0, 0);
            c = __builtin_amdgcn_mfma_f32_16x16x32_bf16(ah[kf], bl, c, 0, 0, 0);
        }
        float bias = b1[cg * 16 + m];
#pragma unroll
        for (int r = 0; r < 4; ++r) {
            float hv = fmaxf(c[r] + bias, 0.f);
            hw[(q * 4 + r) * SH + cg * 16 + m] = hv;   // row=node, col=h-col
        }
    }
    __syncthreads();

    // ---- h -> A frags (hi/lo) ----
    bfrag gh[KF2], gl[KF2];
#pragma unroll
    for (int kf = 0; kf < KF2; ++kf) {
        const float* base = &hw[m * SH + kf * 32 + q * 8];
        float4 u0 = *reinterpret_cast<const float4*>(base);
        float4 u1 = *reinterpret_cast<const float4*>(base + 4);
        float u[8] = {u0.x, u0.y, u0.z, u0.w, u1.x, u1.y, u1.z, u1.w};
#pragma unroll
        for (int j = 0; j < 8; ++j) {
            unsigned short hb = f2bf_rne(u[j]);
            gh[kf][j] = (short)hb;
            gl[kf][j] = (short)f2bf_rne(u[j] - bf2f(hb));
        }
    }

    // ---- phase 2: out = h@W2 + b2 ----
#pragma unroll
    for (int cg = 0; cg < 4; ++cg) {
        ffrag c = {0.f, 0.f, 0.f, 0.f};
#pragma unroll
        for (int kf = 0; kf < KF2; ++kf) {
            bfrag bh = w2hp[(cg * KF2 + kf) * 64 + lane];
            bfrag bl = w2lp[(cg * KF2 + kf) * 64 + lane];
            c = __builtin_amdgcn_mfma_f32_16x16x32_bf16(gh[kf], bh, c, 0, 0, 0);
            c = __builtin_amdgcn_mfma_f32_16x16x32_bf16(gl[kf], bh, c, 0, 0, 0);
            c = __builtin_amdgcn_mfma_f32_16x16x32_bf16(gh[kf], bl, c, 0, 0, 0);
        }
        float bias = b2[cg * 16 + m];
#pragma unroll
        for (int r = 0; r < 4; ++r) {
            int nd = node0 + q * 4 + r;
            if (nd < N) {
                float v = c[r] + bias;
                if (RELU_OUT) v = fmaxf(v, 0.f);
                out[(size_t)nd * FEAT + cg * 16 + m] = v;
            }
        }
    }
}

// ---------------------------------------------------------------------------
extern "C" void kernel_launch(void* const* d_in, const int* in_sizes, int n_in,
                              void* d_out, int out_size, void* d_ws, size_t ws_size,
                              hipStream_t stream) {
    const float* x   = (const float*)d_in[0];
    const int*   ei  = (const int*)  d_in[1];
    const float* ew  = (const float*)d_in[2];
    const float* w11 = (const float*)d_in[3];
    const float* b11 = (const float*)d_in[4];
    const float* w12 = (const float*)d_in[5];
    const float* b12 = (const float*)d_in[6];
    const float* w21 = (const float*)d_in[7];
    const float* b21 = (const float*)d_in[8];
    const float* w22 = (const float*)d_in[9];
    const float* b22 = (const float*)d_in[10];
    const float* w31 = (const float*)d_in[11];
    const float* b31 = (const float*)d_in[12];
    const float* w32 = (const float*)d_in[13];
    const float* b32 = (const float*)d_in[14];

    const int N = in_sizes[0] / FEAT;   // 100000
    const int E = in_sizes[2];          // 1000000
    const int* srci = ei;
    const int* dsti = ei + E;

    // ---- workspace layout ----
    float* agg    = (float*)d_ws;                       // [N*64]
    int*   rowptr = (int*)(agg + (size_t)N * FEAT);     // [N+1]
    int*   pos    = rowptr + (N + 1);                   // [N]
    int*   deg    = pos + N;                            // [N]
    int*   bsums  = deg + N;                            // [512]
    int*   csr_s  = bsums + 512;                        // [E]
    float* csr_w  = (float*)(csr_s + E);                // [E]
    // packed weights (16B aligned)
    size_t pk = ((size_t)(csr_w + E) + 15) & ~(size_t)15;
    unsigned short* p11h = (unsigned short*)pk;         // 4096 each for 64x64
    unsigned short* p11l = p11h + 4096;
    unsigned short* p12h = p11l + 4096;
    unsigned short* p12l = p12h + 4096;
    unsigned short* p21h = p12l + 4096;                 // 8192 for 64x128
    unsigned short* p21l = p21h + 8192;
    unsigned short* p22h = p21l + 8192;                 // 8192 for 128x64
    unsigned short* p22l = p22h + 8192;
    unsigned short* p31h = p22l + 8192;
    unsigned short* p31l = p31h + 4096;
    unsigned short* p32h = p31l + 4096;
    unsigned short* p32l = p32h + 4096;
    float* outF   = (float*)d_out;                      // [N*64]

    const int gE   = (E + 255) / 256;
    const int gN   = (N + 255) / 256;
    const int nb1  = (N + 255) / 256;
    const int gN1  = (N + 1 + 255) / 256;
    const int gGat = (N * 64 + 255) / 256;              // wave per node
    const int gMlp = (N + 63) / 64;

    // ---- CSR build ----
    k_zero <<<gN,  256, 0, stream>>>(deg, N);
    k_hist <<<gE,  256, 0, stream>>>(dsti, deg, E);
    k_scan1<<<nb1, 256, 0, stream>>>(deg, rowptr, bsums, N);
    k_scan2<<<1,   512, 0, stream>>>(bsums, nb1);
    k_add  <<<gN1, 256, 0, stream>>>(rowptr, pos, bsums, N, E);
    k_fill <<<gE,  256, 0, stream>>>(srci, dsti, ew, pos, csr_s, csr_w, E);

    // ---- pack weights (frag order, bf16 hi/lo) ----
    k_pack<<<16, 256, 0, stream>>>(w11, p11h, p11l, 64, 64);
    k_pack<<<16, 256, 0, stream>>>(w12, p12h, p12l, 64, 64);
    k_pack<<<32, 256, 0, stream>>>(w21, p21h, p21l, 64, 128);
    k_pack<<<32, 256, 0, stream>>>(w22, p22h, p22l, 128, 64);
    k_pack<<<16, 256, 0, stream>>>(w31, p31h, p31l, 64, 64);
    k_pack<<<16, 256, 0, stream>>>(w32, p32h, p32l, 64, 64);

    // ---- layer 1 ----
    k_gather2<<<gGat, 256, 0, stream>>>(x, agg, rowptr, csr_s, csr_w, N);
    k_mlp3<64,  true ><<<gMlp, 256, 0, stream>>>(agg, outF, p11h, p11l, b11, p12h, p12l, b12, N);
    // ---- layer 2 ----
    k_gather2<<<gGat, 256, 0, stream>>>(outF, agg, rowptr, csr_s, csr_w, N);
    k_mlp3<128, true ><<<gMlp, 256, 0, stream>>>(agg, outF, p21h, p21l, b21, p22h, p22l, b22, N);
    // ---- layer 3 ----
    k_gather2<<<gGat, 256, 0, stream>>>(outF, agg, rowptr, csr_s, csr_w, N);
    k_mlp3<64,  false><<<gMlp, 256, 0, stream>>>(agg, outF, p31h, p31l, b31, p32h, p32l, b32, N);
}

// Round 5
// 407.043 us; speedup vs baseline: 2.4201x; 1.0623x over previous
//
#include <hip/hip_runtime.h>
#include <math.h>

// ---------------------------------------------------------------------------
// GIN, 3 layers, N=100000, E=1000000, D=64, fp32 in/out.
// Round 5:
//  - CSR payload interleaved as int2 (src, w-bits): one 8B scattered store
//    per edge in k_fill (halves dirtied lines), one dwordx2 read in gather.
//  - Gather: 16 edges/iter (4 slots x 4 unroll), +x load hoisted; most nodes
//    (avg deg 10) finish in one iteration with 4 row-loads in flight/lane.
//  - MFMA bf16x3 MLP + CSR build otherwise unchanged from round 4.
// ---------------------------------------------------------------------------

#define FEAT 64

typedef __attribute__((ext_vector_type(8))) short bfrag;   // 8 bf16 (4 VGPRs)
typedef __attribute__((ext_vector_type(4))) float ffrag;   // 4 fp32 acc

__device__ __forceinline__ unsigned short f2bf_rne(float x) {
    union { float f; unsigned u; } v; v.f = x;
    unsigned r = (v.u + 0x7fffu + ((v.u >> 16) & 1u)) >> 16;
    return (unsigned short)r;
}
__device__ __forceinline__ float bf2f(unsigned short h) {
    union { unsigned u; float f; } v; v.u = ((unsigned)h) << 16;
    return v.f;
}

// ---------------- CSR build ------------------------------------------------
__global__ void k_zero(int* p, int n) {
    int i = blockIdx.x * 256 + threadIdx.x;
    if (i < n) p[i] = 0;
}

__global__ void k_hist(const int* __restrict__ dst, int* __restrict__ deg, int E) {
    int e = blockIdx.x * 256 + threadIdx.x;
    if (e < E) atomicAdd(&deg[dst[e]], 1);
}

__global__ void k_scan1(const int* __restrict__ deg, int* __restrict__ part,
                        int* __restrict__ bsums, int n) {
    __shared__ int tmp[256];
    int tid = threadIdx.x;
    int i = blockIdx.x * 256 + tid;
    int v = (i < n) ? deg[i] : 0;
    tmp[tid] = v;
    __syncthreads();
    for (int off = 1; off < 256; off <<= 1) {
        int t = (tid >= off) ? tmp[tid - off] : 0;
        __syncthreads();
        tmp[tid] += t;
        __syncthreads();
    }
    if (i < n) part[i] = tmp[tid] - v;            // exclusive
    if (tid == 255) bsums[blockIdx.x] = tmp[255]; // block total
}

__global__ void k_scan2(int* bsums, int nb) {
    __shared__ int tmp[512];
    int tid = threadIdx.x;
    int v = (tid < nb) ? bsums[tid] : 0;
    tmp[tid] = v;
    __syncthreads();
    for (int off = 1; off < 512; off <<= 1) {
        int t = (tid >= off) ? tmp[tid - off] : 0;
        __syncthreads();
        tmp[tid] += t;
        __syncthreads();
    }
    if (tid < nb) bsums[tid] = tmp[tid] - v;
}

__global__ void k_add(int* __restrict__ rowptr, int* __restrict__ pos,
                      const int* __restrict__ bsums, int n, int E) {
    int i = blockIdx.x * 256 + threadIdx.x;
    if (i < n) {
        int v = rowptr[i] + bsums[i >> 8];
        rowptr[i] = v;
        pos[i] = v;
    } else if (i == n) {
        rowptr[n] = E;
    }
}

__global__ void k_fill(const int* __restrict__ src, const int* __restrict__ dst,
                       const float* __restrict__ ew, int* __restrict__ pos,
                       int2* __restrict__ csr, int E) {
    int e = blockIdx.x * 256 + threadIdx.x;
    if (e < E) {
        int d = dst[e];
        int slot = atomicAdd(&pos[d], 1);
        csr[slot] = make_int2(src[e], __float_as_int(ew[e]));  // one 8B store
    }
}

// ---------------- weight pack: [K][Hc] fp32 -> B-frag-ordered bf16 hi/lo ---
__global__ void k_pack(const float* __restrict__ w, unsigned short* __restrict__ hi,
                       unsigned short* __restrict__ lo, int K, int Hc) {
    int i = blockIdx.x * 256 + threadIdx.x;
    if (i >= K * Hc) return;
    int KF = K >> 5;
    int j    = i & 7;
    int lane = (i >> 3) & 63;
    int fb   = i >> 9;
    int kf   = fb % KF;
    int cg   = fb / KF;
    int k    = kf * 32 + ((lane >> 4) << 3) + j;
    int col  = cg * 16 + (lane & 15);
    float x = w[k * Hc + col];
    unsigned short h = f2bf_rne(x);
    hi[i] = h;
    lo[i] = f2bf_rne(x - bf2f(h));
}

// ---------------- gather: wave=node, 4 edge-slots x 16 float4-lanes --------
// 16 edges per iteration; avg degree 10 -> usually a single iteration.
__global__ __launch_bounds__(256)
void k_gather2(const float* __restrict__ in, float* __restrict__ agg,
               const int* __restrict__ rowptr, const int2* __restrict__ csr,
               int N) {
    int wid = (blockIdx.x * 256 + threadIdx.x) >> 6;
    int lane = threadIdx.x & 63;
    wid = __builtin_amdgcn_readfirstlane(wid);
    if (wid >= N) return;
    const int qw = lane >> 4;   // edge slot 0..3
    const int f  = lane & 15;   // feature quad
    const int beg = rowptr[wid];
    const int end = rowptr[wid + 1];
    const float4* in4 = reinterpret_cast<const float4*>(in);

    float4 xr = in4[(size_t)wid * 16 + f];   // "+x", independent: issue early

    float4 acc = make_float4(0.f, 0.f, 0.f, 0.f);
    for (int p = beg; p < end; p += 16) {
        int   s[4];
        float w[4];
#pragma unroll
        for (int u = 0; u < 4; ++u) {
            int i = p + 4 * u + qw;
            int2 ev = make_int2(0, 0);
            if (i < end) ev = csr[i];        // one dwordx2
            s[u] = ev.x;
            w[u] = __int_as_float(ev.y);     // 0.0f when inactive
        }
        float4 v[4];
#pragma unroll
        for (int u = 0; u < 4; ++u)
            v[u] = in4[(size_t)s[u] * 16 + f];   // 4 row-loads in flight
#pragma unroll
        for (int u = 0; u < 4; ++u) {
            acc.x = fmaf(w[u], v[u].x, acc.x);
            acc.y = fmaf(w[u], v[u].y, acc.y);
            acc.z = fmaf(w[u], v[u].z, acc.z);
            acc.w = fmaf(w[u], v[u].w, acc.w);
        }
    }
    // butterfly across the 4 edge-slots (lane bits 4,5)
    acc.x += __shfl_xor(acc.x, 16); acc.y += __shfl_xor(acc.y, 16);
    acc.z += __shfl_xor(acc.z, 16); acc.w += __shfl_xor(acc.w, 16);
    acc.x += __shfl_xor(acc.x, 32); acc.y += __shfl_xor(acc.y, 32);
    acc.z += __shfl_xor(acc.z, 32); acc.w += __shfl_xor(acc.w, 32);

    acc.x += xr.x; acc.y += xr.y; acc.z += xr.z; acc.w += xr.w;
    if (qw == 0)
        reinterpret_cast<float4*>(agg)[(size_t)wid * 16 + f] = acc;
}

// ---------------- MFMA MLP: out = relu?(relu(A@W1+b1)@W2+b2) ---------------
// Block 256 = 4 waves, 16 nodes/wave. bf16x3 split precision.
template<int H, bool RELU_OUT>
__global__ __launch_bounds__(256)
void k_mlp3(const float* __restrict__ in, float* __restrict__ out,
            const unsigned short* __restrict__ w1h, const unsigned short* __restrict__ w1l,
            const float* __restrict__ b1,
            const unsigned short* __restrict__ w2h, const unsigned short* __restrict__ w2l,
            const float* __restrict__ b2, int N) {
    constexpr int SH  = H + 4;      // LDS h-row stride: 2-way bank alias only
    constexpr int CG1 = H / 16;     // phase-1 col groups
    constexpr int KF2 = H / 32;     // phase-2 k frags
    __shared__ float hs[4 * 16 * SH];

    const int t = threadIdx.x;
    const int wv = t >> 6, lane = t & 63;
    const int m = lane & 15, q = lane >> 4;
    const int node0 = blockIdx.x * 64 + wv * 16;
    float* hw = &hs[wv * 16 * SH];

    const bfrag* w1hp = reinterpret_cast<const bfrag*>(w1h);
    const bfrag* w1lp = reinterpret_cast<const bfrag*>(w1l);
    const bfrag* w2hp = reinterpret_cast<const bfrag*>(w2h);
    const bfrag* w2lp = reinterpret_cast<const bfrag*>(w2l);

    // ---- load A frags (K=64 -> 2 kf), split hi/lo ----
    bfrag ah[2], al[2];
    const int nodeA = node0 + m;
#pragma unroll
    for (int kf = 0; kf < 2; ++kf) {
        float u[8] = {0.f, 0.f, 0.f, 0.f, 0.f, 0.f, 0.f, 0.f};
        if (nodeA < N) {
            const float* base = in + (size_t)nodeA * FEAT + kf * 32 + q * 8;
            float4 u0 = *reinterpret_cast<const float4*>(base);
            float4 u1 = *reinterpret_cast<const float4*>(base + 4);
            u[0] = u0.x; u[1] = u0.y; u[2] = u0.z; u[3] = u0.w;
            u[4] = u1.x; u[5] = u1.y; u[6] = u1.z; u[7] = u1.w;
        }
#pragma unroll
        for (int j = 0; j < 8; ++j) {
            unsigned short hb = f2bf_rne(u[j]);
            ah[kf][j] = (short)hb;
            al[kf][j] = (short)f2bf_rne(u[j] - bf2f(hb));
        }
    }

    // ---- phase 1: h = relu(A@W1 + b1) -> LDS (wave-private tile) ----
#pragma unroll
    for (int cg = 0; cg < CG1; ++cg) {
        ffrag c = {0.f, 0.f, 0.f, 0.f};
#pragma unroll
        for (int kf = 0; kf < 2; ++kf) {
            bfrag bh = w1hp[(cg * 2 + kf) * 64 + lane];
            bfrag bl = w1lp[(cg * 2 + kf) * 64 + lane];
            c = __builtin_amdgcn_mfma_f32_16x16x32_bf16(ah[kf], bh, c, 0, 0, 0);
            c = __builtin_amdgcn_mfma_f32_16x16x32_bf16(al[kf], bh, c, 0, 0, 0);
            c = __builtin_amdgcn_mfma_f32_16x16x32_bf16(ah[kf], bl, c, 0, 0, 0);
        }
        float bias = b1[cg * 16 + m];
#pragma unroll
        for (int r = 0; r < 4; ++r) {
            float hv = fmaxf(c[r] + bias, 0.f);
            hw[(q * 4 + r) * SH + cg * 16 + m] = hv;   // row=node, col=h-col
        }
    }
    __syncthreads();

    // ---- h -> A frags (hi/lo) ----
    bfrag gh[KF2], gl[KF2];
#pragma unroll
    for (int kf = 0; kf < KF2; ++kf) {
        const float* base = &hw[m * SH + kf * 32 + q * 8];
        float4 u0 = *reinterpret_cast<const float4*>(base);
        float4 u1 = *reinterpret_cast<const float4*>(base + 4);
        float u[8] = {u0.x, u0.y, u0.z, u0.w, u1.x, u1.y, u1.z, u1.w};
#pragma unroll
        for (int j = 0; j < 8; ++j) {
            unsigned short hb = f2bf_rne(u[j]);
            gh[kf][j] = (short)hb;
            gl[kf][j] = (short)f2bf_rne(u[j] - bf2f(hb));
        }
    }

    // ---- phase 2: out = h@W2 + b2 ----
#pragma unroll
    for (int cg = 0; cg < 4; ++cg) {
        ffrag c = {0.f, 0.f, 0.f, 0.f};
#pragma unroll
        for (int kf = 0; kf < KF2; ++kf) {
            bfrag bh = w2hp[(cg * KF2 + kf) * 64 + lane];
            bfrag bl = w2lp[(cg * KF2 + kf) * 64 + lane];
            c = __builtin_amdgcn_mfma_f32_16x16x32_bf16(gh[kf], bh, c, 0, 0, 0);
            c = __builtin_amdgcn_mfma_f32_16x16x32_bf16(gl[kf], bh, c, 0, 0, 0);
            c = __builtin_amdgcn_mfma_f32_16x16x32_bf16(gh[kf], bl, c, 0, 0, 0);
        }
        float bias = b2[cg * 16 + m];
#pragma unroll
        for (int r = 0; r < 4; ++r) {
            int nd = node0 + q * 4 + r;
            if (nd < N) {
                float v = c[r] + bias;
                if (RELU_OUT) v = fmaxf(v, 0.f);
                out[(size_t)nd * FEAT + cg * 16 + m] = v;
            }
        }
    }
}

// ---------------------------------------------------------------------------
extern "C" void kernel_launch(void* const* d_in, const int* in_sizes, int n_in,
                              void* d_out, int out_size, void* d_ws, size_t ws_size,
                              hipStream_t stream) {
    const float* x   = (const float*)d_in[0];
    const int*   ei  = (const int*)  d_in[1];
    const float* ew  = (const float*)d_in[2];
    const float* w11 = (const float*)d_in[3];
    const float* b11 = (const float*)d_in[4];
    const float* w12 = (const float*)d_in[5];
    const float* b12 = (const float*)d_in[6];
    const float* w21 = (const float*)d_in[7];
    const float* b21 = (const float*)d_in[8];
    const float* w22 = (const float*)d_in[9];
    const float* b22 = (const float*)d_in[10];
    const float* w31 = (const float*)d_in[11];
    const float* b31 = (const float*)d_in[12];
    const float* w32 = (const float*)d_in[13];
    const float* b32 = (const float*)d_in[14];

    const int N = in_sizes[0] / FEAT;   // 100000
    const int E = in_sizes[2];          // 1000000
    const int* srci = ei;
    const int* dsti = ei + E;

    // ---- workspace layout ----
    float* agg    = (float*)d_ws;                       // [N*64]
    int*   rowptr = (int*)(agg + (size_t)N * FEAT);     // [N+1]
    int*   pos    = rowptr + (N + 1);                   // [N]
    int*   deg    = pos + N;                            // [N]
    int*   bsums  = deg + N;                            // [512]
    size_t c8 = ((size_t)(bsums + 512) + 7) & ~(size_t)7;
    int2*  csr    = (int2*)c8;                          // [E] interleaved (s,w)
    size_t pk = ((size_t)(csr + E) + 15) & ~(size_t)15;
    unsigned short* p11h = (unsigned short*)pk;         // 4096 each for 64x64
    unsigned short* p11l = p11h + 4096;
    unsigned short* p12h = p11l + 4096;
    unsigned short* p12l = p12h + 4096;
    unsigned short* p21h = p12l + 4096;                 // 8192 for 64x128
    unsigned short* p21l = p21h + 8192;
    unsigned short* p22h = p21l + 8192;                 // 8192 for 128x64
    unsigned short* p22l = p22h + 8192;
    unsigned short* p31h = p22l + 8192;
    unsigned short* p31l = p31h + 4096;
    unsigned short* p32h = p31l + 4096;
    unsigned short* p32l = p32h + 4096;
    float* outF   = (float*)d_out;                      // [N*64]

    const int gE   = (E + 255) / 256;
    const int gN   = (N + 255) / 256;
    const int nb1  = (N + 255) / 256;
    const int gN1  = (N + 1 + 255) / 256;
    const int gGat = (N * 64 + 255) / 256;              // wave per node
    const int gMlp = (N + 63) / 64;

    // ---- CSR build ----
    k_zero <<<gN,  256, 0, stream>>>(deg, N);
    k_hist <<<gE,  256, 0, stream>>>(dsti, deg, E);
    k_scan1<<<nb1, 256, 0, stream>>>(deg, rowptr, bsums, N);
    k_scan2<<<1,   512, 0, stream>>>(bsums, nb1);
    k_add  <<<gN1, 256, 0, stream>>>(rowptr, pos, bsums, N, E);
    k_fill <<<gE,  256, 0, stream>>>(srci, dsti, ew, pos, csr, E);

    // ---- pack weights (frag order, bf16 hi/lo) ----
    k_pack<<<16, 256, 0, stream>>>(w11, p11h, p11l, 64, 64);
    k_pack<<<16, 256, 0, stream>>>(w12, p12h, p12l, 64, 64);
    k_pack<<<32, 256, 0, stream>>>(w21, p21h, p21l, 64, 128);
    k_pack<<<32, 256, 0, stream>>>(w22, p22h, p22l, 128, 64);
    k_pack<<<16, 256, 0, stream>>>(w31, p31h, p31l, 64, 64);
    k_pack<<<16, 256, 0, stream>>>(w32, p32h, p32l, 64, 64);

    // ---- layer 1 ----
    k_gather2<<<gGat, 256, 0, stream>>>(x, agg, rowptr, csr, N);
    k_mlp3<64,  true ><<<gMlp, 256, 0, stream>>>(agg, outF, p11h, p11l, b11, p12h, p12l, b12, N);
    // ---- layer 2 ----
    k_gather2<<<gGat, 256, 0, stream>>>(outF, agg, rowptr, csr, N);
    k_mlp3<128, true ><<<gMlp, 256, 0, stream>>>(agg, outF, p21h, p21l, b21, p22h, p22l, b22, N);
    // ---- layer 3 ----
    k_gather2<<<gGat, 256, 0, stream>>>(outF, agg, rowptr, csr, N);
    k_mlp3<64,  false><<<gMlp, 256, 0, stream>>>(agg, outF, p31h, p31l, b31, p32h, p32l, b32, N);
}